// Round 10
// baseline (63.926 us; speedup 1.0000x reference)
//
#include <hip/hip_runtime.h>
#include <math.h>

#define BATCH 16384
#define EDIM 128
#define RD (EDIM * EDIM)     // 16384 floats = 64 KB
#define NREL 200
#define SPLIT 2
#define NBLK (NREL * SPLIT)  // 400
#define NTHR 512
#define HALF (BATCH / SPLIT) // 8192
#define PERT (HALF / NTHR)   // 16
#define G 16
#define LISTCAP 2048

__device__ __forceinline__ int load_idx(const void* p, int b, int is64) {
    if (is64) return (int)((const long long*)p)[b];
    return ((const int*)p)[b];
}

// Block (rid, half): stage 64KB R in LDS once; find elements; process groups
// of 16 as 4 element-replicas x (8 row-slices x 16 col-lanes).
// Thread: 4 elems x 8 cols x 16 rows -> acc = 8 float4 (32 VGPR), 32 FMA / 32B LDS.
__global__ __launch_bounds__(NTHR, 4) void rescal_kernel(
    const void* __restrict__ hI, const void* __restrict__ rI,
    const void* __restrict__ pI, const void* __restrict__ nI,
    const float* __restrict__ ent, const float* __restrict__ rel,
    float* __restrict__ out) {
    const int t = threadIdx.x;
    const int rid = blockIdx.x >> 1;
    const int half = blockIdx.x & 1;
    const int lane = t & 63;
    const int wave = t >> 6;        // 0..7
    const int l16 = t & 15;
    const int rsel = (t >> 4) & 7;  // 0..7 (row slice: rows rsel*16 .. +15)
    const int rep = t >> 7;         // 0..3 (element replica: elems rep*4 .. +3)
    const int e4 = rep * 4;
    const int c8 = l16 * 8;         // my 8 columns

    __shared__ __attribute__((aligned(16))) float Rl[RD];   // 64 KB
    __shared__ float hL[G][EDIM + 1];                       // 8.25 KB, padded rows
    __shared__ unsigned short list[LISTCAP];                // 4 KB
    __shared__ float red[8][3][4];                          // per-wave partials
    __shared__ float h2a[G];
    __shared__ unsigned int wtot[8], um8[8];
    __shared__ float wred[8];
    __shared__ float s_bsum;

    // ---- dtype detect ----
    unsigned int o = 0u;
    if (t < 256) {
        o = ((const unsigned int*)hI)[2 * t + 1] | ((const unsigned int*)rI)[2 * t + 1] |
            ((const unsigned int*)pI)[2 * t + 1] | ((const unsigned int*)nI)[2 * t + 1];
    }
#pragma unroll
    for (int off = 32; off; off >>= 1) o |= __shfl_xor(o, off, 64);
    if (lane == 0) um8[wave] = o;
    if (t == 0) s_bsum = 0.f;
    __syncthreads();
    const int is64 = ((um8[0] | um8[1] | um8[2] | um8[3] |
                       um8[4] | um8[5] | um8[6] | um8[7]) == 0u) ? 1 : 0;

    // ---- stage R to LDS (coalesced float4) ----
    const float* Rg = rel + (size_t)rid * RD;
#pragma unroll
    for (int it = 0; it < 8; ++it) {
        const int idx = it * (NTHR * 4) + t * 4;
        *(float4*)&Rl[idx] = *(const float4*)(Rg + idx);
    }

    // ---- find my elements in my batch-half (deterministic) ----
    const int base0 = half * HALF + t * PERT;
    int rv[PERT];
    int cl = 0;
#pragma unroll
    for (int j = 0; j < PERT; ++j) {
        rv[j] = load_idx(rI, base0 + j, is64);
        cl += (rv[j] == rid);
    }
    int incl = cl;
#pragma unroll
    for (int off = 1; off < 64; off <<= 1) {
        const int nv = __shfl_up(incl, off, 64);
        if (lane >= off) incl += nv;
    }
    if (lane == 63) wtot[wave] = (unsigned int)incl;
    __syncthreads();  // Rl + wtot ready
    int base = 0, cnt = 0;
#pragma unroll
    for (int w = 0; w < 8; ++w) {
        const int wv = (int)wtot[w];
        base += (w < wave) ? wv : 0;
        cnt += wv;
    }
    if (cnt > LISTCAP) cnt = LISTCAP;
    {
        int rk = base + incl - cl;
#pragma unroll
        for (int j = 0; j < PERT; ++j) {
            if (rv[j] == rid) {
                if (rk < LISTCAP) list[rk] = (unsigned short)(base0 + j);
                ++rk;
            }
        }
    }

    // ---- r2 from LDS copy (contiguous, conflict-free) ----
    {
        float r2p = 0.f;
#pragma unroll
        for (int j = 0; j < 8; ++j) {
            const float4 v = *(const float4*)&Rl[j * (NTHR * 4) + t * 4];
            r2p = fmaf(v.x, v.x, fmaf(v.y, v.y, fmaf(v.z, v.z, fmaf(v.w, v.w, r2p))));
        }
#pragma unroll
        for (int off = 32; off; off >>= 1) r2p += __shfl_down(r2p, off, 64);
        if (lane == 0) wred[wave] = r2p;
    }
    __syncthreads();  // list + wred ready
    float r2sum = 0.f;
#pragma unroll
    for (int w = 0; w < 8; ++w) r2sum += wred[w];

    // ---- groups of G=16 elements ----
    for (int g0 = 0; g0 < cnt; g0 += G) {
        const int cg = (cnt - g0 < G) ? (cnt - g0) : G;

        // stage h rows (row-major, padded): 32 lanes per element
        {
            const int g = t >> 5, l = t & 31;
            if (g < cg) {
                const int b = (int)list[g0 + g];
                const int hi = load_idx(hI, b, is64);
                const float4 hv = *(const float4*)(ent + (size_t)hi * EDIM + l * 4);
                hL[g][4 * l + 0] = hv.x;
                hL[g][4 * l + 1] = hv.y;
                hL[g][4 * l + 2] = hv.z;
                hL[g][4 * l + 3] = hv.w;
                float h2 = hv.x * hv.x + hv.y * hv.y + hv.z * hv.z + hv.w * hv.w;
                h2 += __shfl_xor(h2, 16, 64);
                h2 += __shfl_xor(h2, 8, 64);
                h2 += __shfl_xor(h2, 4, 64);
                h2 += __shfl_xor(h2, 2, 64);
                h2 += __shfl_xor(h2, 1, 64);
                if (l == 0) h2a[g] = h2;
            } else {
                hL[g][4 * l + 0] = 0.f;
                hL[g][4 * l + 1] = 0.f;
                hL[g][4 * l + 2] = 0.f;
                hL[g][4 * l + 3] = 0.f;
            }
        }
        __syncthreads();

        // compute: partial u over my 16 rows x 8 cols for 4 elements
        float4 acc[4][2];
#pragma unroll
        for (int i = 0; i < 4; ++i) {
            acc[i][0] = make_float4(0.f, 0.f, 0.f, 0.f);
            acc[i][1] = make_float4(0.f, 0.f, 0.f, 0.f);
        }
#pragma unroll 4
        for (int k = 0; k < 16; ++k) {
            const int d = rsel * 16 + k;
            const float4 r0 = *(const float4*)&Rl[d * EDIM + c8];
            const float4 r1 = *(const float4*)&Rl[d * EDIM + c8 + 4];
            const float hd0 = hL[e4 + 0][d];
            const float hd1 = hL[e4 + 1][d];
            const float hd2 = hL[e4 + 2][d];
            const float hd3 = hL[e4 + 3][d];
            acc[0][0].x = fmaf(r0.x, hd0, acc[0][0].x);
            acc[0][0].y = fmaf(r0.y, hd0, acc[0][0].y);
            acc[0][0].z = fmaf(r0.z, hd0, acc[0][0].z);
            acc[0][0].w = fmaf(r0.w, hd0, acc[0][0].w);
            acc[0][1].x = fmaf(r1.x, hd0, acc[0][1].x);
            acc[0][1].y = fmaf(r1.y, hd0, acc[0][1].y);
            acc[0][1].z = fmaf(r1.z, hd0, acc[0][1].z);
            acc[0][1].w = fmaf(r1.w, hd0, acc[0][1].w);
            acc[1][0].x = fmaf(r0.x, hd1, acc[1][0].x);
            acc[1][0].y = fmaf(r0.y, hd1, acc[1][0].y);
            acc[1][0].z = fmaf(r0.z, hd1, acc[1][0].z);
            acc[1][0].w = fmaf(r0.w, hd1, acc[1][0].w);
            acc[1][1].x = fmaf(r1.x, hd1, acc[1][1].x);
            acc[1][1].y = fmaf(r1.y, hd1, acc[1][1].y);
            acc[1][1].z = fmaf(r1.z, hd1, acc[1][1].z);
            acc[1][1].w = fmaf(r1.w, hd1, acc[1][1].w);
            acc[2][0].x = fmaf(r0.x, hd2, acc[2][0].x);
            acc[2][0].y = fmaf(r0.y, hd2, acc[2][0].y);
            acc[2][0].z = fmaf(r0.z, hd2, acc[2][0].z);
            acc[2][0].w = fmaf(r0.w, hd2, acc[2][0].w);
            acc[2][1].x = fmaf(r1.x, hd2, acc[2][1].x);
            acc[2][1].y = fmaf(r1.y, hd2, acc[2][1].y);
            acc[2][1].z = fmaf(r1.z, hd2, acc[2][1].z);
            acc[2][1].w = fmaf(r1.w, hd2, acc[2][1].w);
            acc[3][0].x = fmaf(r0.x, hd3, acc[3][0].x);
            acc[3][0].y = fmaf(r0.y, hd3, acc[3][0].y);
            acc[3][0].z = fmaf(r0.z, hd3, acc[3][0].z);
            acc[3][0].w = fmaf(r0.w, hd3, acc[3][0].w);
            acc[3][1].x = fmaf(r1.x, hd3, acc[3][1].x);
            acc[3][1].y = fmaf(r1.y, hd3, acc[3][1].y);
            acc[3][1].z = fmaf(r1.z, hd3, acc[3][1].z);
            acc[3][1].w = fmaf(r1.w, hd3, acc[3][1].w);
        }

        // tails: partial dots over my cols/rows; e2 gated to rsel==0
        float dp[4], dn[4], e2t[4];
#pragma unroll
        for (int i = 0; i < 4; ++i) {
            const int gi = e4 + i;
            const int li = g0 + ((gi < cg) ? gi : 0);
            const int b = (int)list[li];
            const int pi = load_idx(pI, b, is64);
            const int ni = load_idx(nI, b, is64);
            const float4 tp0 = *(const float4*)(ent + (size_t)pi * EDIM + c8);
            const float4 tp1 = *(const float4*)(ent + (size_t)pi * EDIM + c8 + 4);
            const float4 tn0 = *(const float4*)(ent + (size_t)ni * EDIM + c8);
            const float4 tn1 = *(const float4*)(ent + (size_t)ni * EDIM + c8 + 4);
            dp[i] = acc[i][0].x * tp0.x + acc[i][0].y * tp0.y + acc[i][0].z * tp0.z +
                    acc[i][0].w * tp0.w + acc[i][1].x * tp1.x + acc[i][1].y * tp1.y +
                    acc[i][1].z * tp1.z + acc[i][1].w * tp1.w;
            dn[i] = acc[i][0].x * tn0.x + acc[i][0].y * tn0.y + acc[i][0].z * tn0.z +
                    acc[i][0].w * tn0.w + acc[i][1].x * tn1.x + acc[i][1].y * tn1.y +
                    acc[i][1].z * tn1.z + acc[i][1].w * tn1.w;
            e2t[i] = (rsel == 0)
                         ? (tp0.x * tp0.x + tp0.y * tp0.y + tp0.z * tp0.z + tp0.w * tp0.w +
                            tp1.x * tp1.x + tp1.y * tp1.y + tp1.z * tp1.z + tp1.w * tp1.w +
                            tn0.x * tn0.x + tn0.y * tn0.y + tn0.z * tn0.z + tn0.w * tn0.w +
                            tn1.x * tn1.x + tn1.y * tn1.y + tn1.z * tn1.z + tn1.w * tn1.w)
                         : 0.f;
        }
#pragma unroll
        for (int off = 1; off < 64; off <<= 1) {
#pragma unroll
            for (int i = 0; i < 4; ++i) {
                dp[i] += __shfl_xor(dp[i], off, 64);
                dn[i] += __shfl_xor(dn[i], off, 64);
                e2t[i] += __shfl_xor(e2t[i], off, 64);
            }
        }
        if (lane == 0) {
#pragma unroll
            for (int i = 0; i < 4; ++i) {
                red[wave][0][i] = dp[i];
                red[wave][1][i] = dn[i];
                red[wave][2][i] = e2t[i];
            }
        }
        __syncthreads();

        float s = 0.f;
        if (t < cg) {
            const int w0 = (t >> 2) * 2;  // element t -> waves w0, w0+1
            const int i = t & 3;
            const float SP = red[w0][0][i] + red[w0 + 1][0][i];
            const float SN = red[w0][1][i] + red[w0 + 1][1][i];
            const float E2 = h2a[t] + red[w0][2][i] + red[w0 + 1][2][i];
            const float x = SN - SP;  // neg_score - pos_score
            const float spl = (x > 0.f) ? (x + log1pf(expf(-x))) : log1pf(expf(x));
            s = spl + 1e-5f * 0.5f * (E2 + r2sum);
        }
        if (t < 16) {
            s += __shfl_down(s, 8, 64);
            s += __shfl_down(s, 4, 64);
            s += __shfl_down(s, 2, 64);
            s += __shfl_down(s, 1, 64);
            if (t == 0) s_bsum += s;
        }
        __syncthreads();  // hL/red reusable next group
    }

    if (t == 0 && cnt > 0) atomicAdd(out, s_bsum * (1.0f / (float)BATCH));
}

extern "C" void kernel_launch(void* const* d_in, const int* in_sizes, int n_in,
                              void* d_out, int out_size, void* d_ws, size_t ws_size,
                              hipStream_t stream) {
    const void* h = d_in[0];
    const void* r = d_in[1];
    const void* pt = d_in[2];
    const void* nt = d_in[3];
    const float* ent = (const float*)d_in[4];
    const float* rel = (const float*)d_in[5];

    hipMemsetAsync(d_out, 0, sizeof(float), stream);  // capture-legal
    rescal_kernel<<<NBLK, NTHR, 0, stream>>>(h, r, pt, nt, ent, rel, (float*)d_out);
}

// Round 11
// 60.645 us; speedup vs baseline: 1.0541x; 1.0541x over previous
//
#include <hip/hip_runtime.h>
#include <math.h>

#define BATCH 16384
#define EDIM 128
#define RD (EDIM * EDIM)      // 16384 floats = 64 KB
#define NREL 200
#define SPLIT 4
#define NBLK (NREL * SPLIT)   // 800
#define NTHR 256
#define QUARTER (BATCH / SPLIT)  // 4096
#define PERT (QUARTER / NTHR)    // 16
#define EB 8
#define LISTCAP 256

__device__ __forceinline__ int load_idx(const void* p, int b, int is64) {
    if (is64) return (int)((const long long*)p)[b];
    return ((const int*)p)[b];
}

// Block (rid, quarter): finds its elements in its quarter of the batch, then
// each of the 4 waves independently processes up to 8 elements per batch:
// h rows via wave-uniform scalar loads (SGPR broadcast), R streamed from
// global (coalesced 512B/instr, shared by L1/L2 across waves of the block),
// tails loaded once per element. No LDS tiles, no steady-state barriers.
__global__ __launch_bounds__(NTHR) void rescal_kernel(
    const void* __restrict__ hI, const void* __restrict__ rI,
    const void* __restrict__ pI, const void* __restrict__ nI,
    const float* __restrict__ ent, const float* __restrict__ rel,
    float* __restrict__ out) {
    const int t = threadIdx.x;
    const int bid = blockIdx.x;
    const int rid = bid >> 2;
    const int qtr = bid & 3;
    const int lane = t & 63;
    const int wave = t >> 6;
    const int c2 = lane * 2;

    __shared__ unsigned short list[LISTCAP];
    __shared__ unsigned int wtot[4], um4[4];
    __shared__ float wsum[4];

    // ---- dtype detect ----
    unsigned int o = ((const unsigned int*)hI)[2 * t + 1] |
                     ((const unsigned int*)rI)[2 * t + 1] |
                     ((const unsigned int*)pI)[2 * t + 1] |
                     ((const unsigned int*)nI)[2 * t + 1];
#pragma unroll
    for (int off = 32; off; off >>= 1) o |= __shfl_xor(o, off, 64);
    if (lane == 0) um4[wave] = o;
    __syncthreads();
    const int is64 = ((um4[0] | um4[1] | um4[2] | um4[3]) == 0u) ? 1 : 0;

    // ---- find my elements in my quarter (deterministic scan) ----
    const int base0 = qtr * QUARTER + t * PERT;
    int rv[PERT];
    int cl = 0;
#pragma unroll
    for (int j = 0; j < PERT; ++j) {
        rv[j] = load_idx(rI, base0 + j, is64);
        cl += (rv[j] == rid);
    }
    int incl = cl;
#pragma unroll
    for (int off = 1; off < 64; off <<= 1) {
        const int nv = __shfl_up(incl, off, 64);
        if (lane >= off) incl += nv;
    }
    if (lane == 63) wtot[wave] = (unsigned int)incl;
    __syncthreads();
    int base = 0, cnt = 0;
#pragma unroll
    for (int w = 0; w < 4; ++w) {
        const int wv = (int)wtot[w];
        base += (w < wave) ? wv : 0;
        cnt += wv;
    }
    if (cnt > LISTCAP) cnt = LISTCAP;
    {
        int rk = base + incl - cl;
#pragma unroll
        for (int j = 0; j < PERT; ++j) {
            if (rv[j] == rid) {
                if (rk < LISTCAP) list[rk] = (unsigned short)(base0 + j);
                ++rk;
            }
        }
    }
    __syncthreads();  // list complete; no more block-wide syncs until epilogue

    // ---- per-wave independent range ----
    const int per_wave = (cnt + 3) >> 2;
    int lo = wave * per_wave;
    int hi = (wave + 1) * per_wave;
    if (lo > cnt) lo = cnt;
    if (hi > cnt) hi = cnt;

    const float* Rg = rel + (size_t)rid * RD;
    float lsum = 0.f;   // lane-0 meaningful
    float r2w = 0.f;    // lane-0 meaningful

    for (int e0 = lo; e0 < hi; e0 += EB) {
        // uniform element handles (clamped; dups masked at accumulate)
        int bidx[EB];
        const float* hrow[EB];
#pragma unroll
        for (int i = 0; i < EB; ++i) {
            int e = e0 + i;
            if (e >= hi) e = hi - 1;
            int b = (int)list[e];
            b = __builtin_amdgcn_readfirstlane(b);
            bidx[i] = b;
            int hix = load_idx(hI, b, is64);
            hix = __builtin_amdgcn_readfirstlane(hix);
            hrow[i] = ent + (size_t)hix * EDIM;
        }

        // d-loop: R streamed (coalesced), h via uniform scalar loads
        float2 acc[EB];
#pragma unroll
        for (int i = 0; i < EB; ++i) acc[i] = make_float2(0.f, 0.f);
        float r2p = 0.f;
#pragma unroll 4
        for (int db = 0; db < 32; ++db) {
            float4 hv0 = *(const float4*)(hrow[0] + db * 4);
            float4 hv1 = *(const float4*)(hrow[1] + db * 4);
            float4 hv2 = *(const float4*)(hrow[2] + db * 4);
            float4 hv3 = *(const float4*)(hrow[3] + db * 4);
            float4 hv4 = *(const float4*)(hrow[4] + db * 4);
            float4 hv5 = *(const float4*)(hrow[5] + db * 4);
            float4 hv6 = *(const float4*)(hrow[6] + db * 4);
            float4 hv7 = *(const float4*)(hrow[7] + db * 4);
#pragma unroll
            for (int jj = 0; jj < 4; ++jj) {
                const int d = db * 4 + jj;
                const float2 r2v = *(const float2*)(Rg + d * EDIM + c2);
                r2p = fmaf(r2v.x, r2v.x, fmaf(r2v.y, r2v.y, r2p));
                const float h0 = (jj == 0) ? hv0.x : (jj == 1) ? hv0.y : (jj == 2) ? hv0.z : hv0.w;
                const float h1 = (jj == 0) ? hv1.x : (jj == 1) ? hv1.y : (jj == 2) ? hv1.z : hv1.w;
                const float h2 = (jj == 0) ? hv2.x : (jj == 1) ? hv2.y : (jj == 2) ? hv2.z : hv2.w;
                const float h3 = (jj == 0) ? hv3.x : (jj == 1) ? hv3.y : (jj == 2) ? hv3.z : hv3.w;
                const float h4 = (jj == 0) ? hv4.x : (jj == 1) ? hv4.y : (jj == 2) ? hv4.z : hv4.w;
                const float h5 = (jj == 0) ? hv5.x : (jj == 1) ? hv5.y : (jj == 2) ? hv5.z : hv5.w;
                const float h6 = (jj == 0) ? hv6.x : (jj == 1) ? hv6.y : (jj == 2) ? hv6.z : hv6.w;
                const float h7 = (jj == 0) ? hv7.x : (jj == 1) ? hv7.y : (jj == 2) ? hv7.z : hv7.w;
                acc[0].x = fmaf(r2v.x, h0, acc[0].x); acc[0].y = fmaf(r2v.y, h0, acc[0].y);
                acc[1].x = fmaf(r2v.x, h1, acc[1].x); acc[1].y = fmaf(r2v.y, h1, acc[1].y);
                acc[2].x = fmaf(r2v.x, h2, acc[2].x); acc[2].y = fmaf(r2v.y, h2, acc[2].y);
                acc[3].x = fmaf(r2v.x, h3, acc[3].x); acc[3].y = fmaf(r2v.y, h3, acc[3].y);
                acc[4].x = fmaf(r2v.x, h4, acc[4].x); acc[4].y = fmaf(r2v.y, h4, acc[4].y);
                acc[5].x = fmaf(r2v.x, h5, acc[5].x); acc[5].y = fmaf(r2v.y, h5, acc[5].y);
                acc[6].x = fmaf(r2v.x, h6, acc[6].x); acc[6].y = fmaf(r2v.y, h6, acc[6].y);
                acc[7].x = fmaf(r2v.x, h7, acc[7].x); acc[7].y = fmaf(r2v.y, h7, acc[7].y);
            }
        }
        // r2 of the relation row (identical every batch; reduce to lane 0)
#pragma unroll
        for (int off = 32; off; off >>= 1) r2p += __shfl_xor(r2p, off, 64);
        r2w = r2p;

        // tails: one pass per element, coalesced 512B rows, reduce to lane 0
#pragma unroll
        for (int i = 0; i < EB; ++i) {
            const int b = bidx[i];
            int pi = __builtin_amdgcn_readfirstlane(load_idx(pI, b, is64));
            int ni = __builtin_amdgcn_readfirstlane(load_idx(nI, b, is64));
            const float2 hv2 = *(const float2*)(hrow[i] + c2);
            const float2 tp2 = *(const float2*)(ent + (size_t)pi * EDIM + c2);
            const float2 tn2 = *(const float2*)(ent + (size_t)ni * EDIM + c2);
            float dp = acc[i].x * tp2.x + acc[i].y * tp2.y;
            float dn = acc[i].x * tn2.x + acc[i].y * tn2.y;
            float e2 = hv2.x * hv2.x + hv2.y * hv2.y + tp2.x * tp2.x + tp2.y * tp2.y +
                       tn2.x * tn2.x + tn2.y * tn2.y;
#pragma unroll
            for (int off = 32; off; off >>= 1) {
                dp += __shfl_xor(dp, off, 64);
                dn += __shfl_xor(dn, off, 64);
                e2 += __shfl_xor(e2, off, 64);
            }
            if (lane == 0 && (e0 + i) < hi) {
                const float x = dn - dp;  // neg_score - pos_score
                const float spl = (x > 0.f) ? (x + log1pf(expf(-x))) : log1pf(expf(x));
                lsum += spl + 1e-5f * 0.5f * (e2 + r2w);
            }
        }
    }

    // ---- epilogue: combine 4 wave sums, one atomic per block ----
    if (lane == 0) wsum[wave] = lsum;
    __syncthreads();
    if (t == 0) {
        const float s = wsum[0] + wsum[1] + wsum[2] + wsum[3];
        atomicAdd(out, s * (1.0f / (float)BATCH));
    }
}

extern "C" void kernel_launch(void* const* d_in, const int* in_sizes, int n_in,
                              void* d_out, int out_size, void* d_ws, size_t ws_size,
                              hipStream_t stream) {
    const void* h = d_in[0];
    const void* r = d_in[1];
    const void* pt = d_in[2];
    const void* nt = d_in[3];
    const float* ent = (const float*)d_in[4];
    const float* rel = (const float*)d_in[5];

    hipMemsetAsync(d_out, 0, sizeof(float), stream);  // capture-legal
    rescal_kernel<<<NBLK, NTHR, 0, stream>>>(h, r, pt, nt, ent, rel, (float*)d_out);
}

// Round 12
// 56.572 us; speedup vs baseline: 1.1300x; 1.0720x over previous
//
#include <hip/hip_runtime.h>
#include <math.h>

#define BATCH 16384
#define EDIM 128
#define RD (EDIM * EDIM)      // 16384 floats = 64 KB
#define NREL 200
#define SPLIT 4
#define NBLK (NREL * SPLIT)   // 800
#define NTHR 256
#define QUARTER (BATCH / SPLIT)  // 4096
#define PERT (QUARTER / NTHR)    // 16
#define EB 8
#define LISTCAP 256

// ws layout (floats): csum[0 .. NBLK) — per-block partial sums (plain stores)

__device__ __forceinline__ int load_idx(const void* p, int b, int is64) {
    if (is64) return (int)((const long long*)p)[b];
    return ((const int*)p)[b];
}

__global__ __launch_bounds__(NTHR) void rescal_kernel(
    const void* __restrict__ hI, const void* __restrict__ rI,
    const void* __restrict__ pI, const void* __restrict__ nI,
    const float* __restrict__ ent, const float* __restrict__ rel,
    float* __restrict__ csum) {
    const int t = threadIdx.x;
    const int bid = blockIdx.x;
    const int rid = bid >> 2;
    const int qtr = bid & 3;
    const int lane = t & 63;
    const int wave = t >> 6;
    const int c2 = lane * 2;

    __shared__ unsigned short list[LISTCAP];
    __shared__ unsigned int wtot[4], um4[4];
    __shared__ float wsum[4];

    // ---- dtype detect ----
    unsigned int o = ((const unsigned int*)hI)[2 * t + 1] |
                     ((const unsigned int*)rI)[2 * t + 1] |
                     ((const unsigned int*)pI)[2 * t + 1] |
                     ((const unsigned int*)nI)[2 * t + 1];
#pragma unroll
    for (int off = 32; off; off >>= 1) o |= __shfl_xor(o, off, 64);
    if (lane == 0) um4[wave] = o;
    __syncthreads();
    const int is64 = ((um4[0] | um4[1] | um4[2] | um4[3]) == 0u) ? 1 : 0;

    // ---- find my elements in my quarter (deterministic scan) ----
    const int base0 = qtr * QUARTER + t * PERT;
    int rv[PERT];
    int cl = 0;
#pragma unroll
    for (int j = 0; j < PERT; ++j) {
        rv[j] = load_idx(rI, base0 + j, is64);
        cl += (rv[j] == rid);
    }
    int incl = cl;
#pragma unroll
    for (int off = 1; off < 64; off <<= 1) {
        const int nv = __shfl_up(incl, off, 64);
        if (lane >= off) incl += nv;
    }
    if (lane == 63) wtot[wave] = (unsigned int)incl;
    __syncthreads();
    int base = 0, cnt = 0;
#pragma unroll
    for (int w = 0; w < 4; ++w) {
        const int wv = (int)wtot[w];
        base += (w < wave) ? wv : 0;
        cnt += wv;
    }
    if (cnt > LISTCAP) cnt = LISTCAP;
    {
        int rk = base + incl - cl;
#pragma unroll
        for (int j = 0; j < PERT; ++j) {
            if (rv[j] == rid) {
                if (rk < LISTCAP) list[rk] = (unsigned short)(base0 + j);
                ++rk;
            }
        }
    }
    __syncthreads();  // list complete; no more block syncs until epilogue

    // ---- per-wave independent range ----
    const int per_wave = (cnt + 3) >> 2;
    int lo = wave * per_wave;
    int hi = (wave + 1) * per_wave;
    if (lo > cnt) lo = cnt;
    if (hi > cnt) hi = cnt;

    const float* Rg = rel + (size_t)rid * RD;
    float lsum = 0.f;   // lane-0 meaningful
    float r2w = 0.f;

    for (int e0 = lo; e0 < hi; e0 += EB) {
        int bidx[EB];
        const float* hrow[EB];
#pragma unroll
        for (int i = 0; i < EB; ++i) {
            int e = e0 + i;
            if (e >= hi) e = hi - 1;
            int b = (int)list[e];
            b = __builtin_amdgcn_readfirstlane(b);
            bidx[i] = b;
            int hix = load_idx(hI, b, is64);
            hix = __builtin_amdgcn_readfirstlane(hix);
            hrow[i] = ent + (size_t)hix * EDIM;
        }

        float2 acc[EB];
#pragma unroll
        for (int i = 0; i < EB; ++i) acc[i] = make_float2(0.f, 0.f);
        float r2p = 0.f;
#pragma unroll 4
        for (int db = 0; db < 32; ++db) {
            float4 hv0 = *(const float4*)(hrow[0] + db * 4);
            float4 hv1 = *(const float4*)(hrow[1] + db * 4);
            float4 hv2 = *(const float4*)(hrow[2] + db * 4);
            float4 hv3 = *(const float4*)(hrow[3] + db * 4);
            float4 hv4 = *(const float4*)(hrow[4] + db * 4);
            float4 hv5 = *(const float4*)(hrow[5] + db * 4);
            float4 hv6 = *(const float4*)(hrow[6] + db * 4);
            float4 hv7 = *(const float4*)(hrow[7] + db * 4);
#pragma unroll
            for (int jj = 0; jj < 4; ++jj) {
                const int d = db * 4 + jj;
                const float2 r2v = *(const float2*)(Rg + d * EDIM + c2);
                r2p = fmaf(r2v.x, r2v.x, fmaf(r2v.y, r2v.y, r2p));
                const float h0 = (jj == 0) ? hv0.x : (jj == 1) ? hv0.y : (jj == 2) ? hv0.z : hv0.w;
                const float h1 = (jj == 0) ? hv1.x : (jj == 1) ? hv1.y : (jj == 2) ? hv1.z : hv1.w;
                const float h2 = (jj == 0) ? hv2.x : (jj == 1) ? hv2.y : (jj == 2) ? hv2.z : hv2.w;
                const float h3 = (jj == 0) ? hv3.x : (jj == 1) ? hv3.y : (jj == 2) ? hv3.z : hv3.w;
                const float h4 = (jj == 0) ? hv4.x : (jj == 1) ? hv4.y : (jj == 2) ? hv4.z : hv4.w;
                const float h5 = (jj == 0) ? hv5.x : (jj == 1) ? hv5.y : (jj == 2) ? hv5.z : hv5.w;
                const float h6 = (jj == 0) ? hv6.x : (jj == 1) ? hv6.y : (jj == 2) ? hv6.z : hv6.w;
                const float h7 = (jj == 0) ? hv7.x : (jj == 1) ? hv7.y : (jj == 2) ? hv7.z : hv7.w;
                acc[0].x = fmaf(r2v.x, h0, acc[0].x); acc[0].y = fmaf(r2v.y, h0, acc[0].y);
                acc[1].x = fmaf(r2v.x, h1, acc[1].x); acc[1].y = fmaf(r2v.y, h1, acc[1].y);
                acc[2].x = fmaf(r2v.x, h2, acc[2].x); acc[2].y = fmaf(r2v.y, h2, acc[2].y);
                acc[3].x = fmaf(r2v.x, h3, acc[3].x); acc[3].y = fmaf(r2v.y, h3, acc[3].y);
                acc[4].x = fmaf(r2v.x, h4, acc[4].x); acc[4].y = fmaf(r2v.y, h4, acc[4].y);
                acc[5].x = fmaf(r2v.x, h5, acc[5].x); acc[5].y = fmaf(r2v.y, h5, acc[5].y);
                acc[6].x = fmaf(r2v.x, h6, acc[6].x); acc[6].y = fmaf(r2v.y, h6, acc[6].y);
                acc[7].x = fmaf(r2v.x, h7, acc[7].x); acc[7].y = fmaf(r2v.y, h7, acc[7].y);
            }
        }
#pragma unroll
        for (int off = 32; off; off >>= 1) r2p += __shfl_xor(r2p, off, 64);
        r2w = r2p;

#pragma unroll
        for (int i = 0; i < EB; ++i) {
            const int b = bidx[i];
            int pi = __builtin_amdgcn_readfirstlane(load_idx(pI, b, is64));
            int ni = __builtin_amdgcn_readfirstlane(load_idx(nI, b, is64));
            const float2 hv2 = *(const float2*)(hrow[i] + c2);
            const float2 tp2 = *(const float2*)(ent + (size_t)pi * EDIM + c2);
            const float2 tn2 = *(const float2*)(ent + (size_t)ni * EDIM + c2);
            float dp = acc[i].x * tp2.x + acc[i].y * tp2.y;
            float dn = acc[i].x * tn2.x + acc[i].y * tn2.y;
            float e2 = hv2.x * hv2.x + hv2.y * hv2.y + tp2.x * tp2.x + tp2.y * tp2.y +
                       tn2.x * tn2.x + tn2.y * tn2.y;
#pragma unroll
            for (int off = 32; off; off >>= 1) {
                dp += __shfl_xor(dp, off, 64);
                dn += __shfl_xor(dn, off, 64);
                e2 += __shfl_xor(e2, off, 64);
            }
            if (lane == 0 && (e0 + i) < hi) {
                const float x = dn - dp;  // neg_score - pos_score
                const float spl = (x > 0.f) ? (x + log1pf(expf(-x))) : log1pf(expf(x));
                lsum += spl + 1e-5f * 0.5f * (e2 + r2w);
            }
        }
    }

    // ---- epilogue: plain store of block partial (unconditional: poison-safe) ----
    if (lane == 0) wsum[wave] = lsum;
    __syncthreads();
    if (t == 0) csum[bid] = wsum[0] + wsum[1] + wsum[2] + wsum[3];
}

__global__ __launch_bounds__(NTHR) void reduce_kernel(const float* __restrict__ csum,
                                                      float* __restrict__ out) {
    const int t = threadIdx.x;
    float a = 0.f;
    for (int i = t; i < NBLK; i += NTHR) a += csum[i];
#pragma unroll
    for (int off = 32; off; off >>= 1) a += __shfl_down(a, off, 64);
    __shared__ float sm[4];
    if ((t & 63) == 0) sm[t >> 6] = a;
    __syncthreads();
    if (t == 0) out[0] = (sm[0] + sm[1] + sm[2] + sm[3]) * (1.0f / (float)BATCH);
}

extern "C" void kernel_launch(void* const* d_in, const int* in_sizes, int n_in,
                              void* d_out, int out_size, void* d_ws, size_t ws_size,
                              hipStream_t stream) {
    const void* h = d_in[0];
    const void* r = d_in[1];
    const void* pt = d_in[2];
    const void* nt = d_in[3];
    const float* ent = (const float*)d_in[4];
    const float* rel = (const float*)d_in[5];
    float* csum = (float*)d_ws;

    rescal_kernel<<<NBLK, NTHR, 0, stream>>>(h, r, pt, nt, ent, rel, csum);
    reduce_kernel<<<1, NTHR, 0, stream>>>(csum, (float*)d_out);
}

// Round 13
// 54.095 us; speedup vs baseline: 1.1817x; 1.0458x over previous
//
#include <hip/hip_runtime.h>
#include <math.h>

#define BATCH 16384
#define EDIM 128
#define RD (EDIM * EDIM)      // 16384 floats = 64 KB
#define NREL 200
#define SPLIT 4
#define NBLK (NREL * SPLIT)   // 800
#define NTHR 256
#define QUARTER (BATCH / SPLIT)  // 4096
#define NJ (QUARTER / NTHR)      // 16
#define EB 8
#define LISTCAP 256

// ws layout (floats): csum[0 .. NBLK) — per-block partial sums (plain stores)

__device__ __forceinline__ int load_idx(const void* p, int b, int is64) {
    if (is64) return (int)((const long long*)p)[b];
    return ((const int*)p)[b];
}

__global__ __launch_bounds__(NTHR) void rescal_kernel(
    const void* __restrict__ hI, const void* __restrict__ rI,
    const void* __restrict__ pI, const void* __restrict__ nI,
    const float* __restrict__ ent, const float* __restrict__ rel,
    float* __restrict__ csum) {
    const int t = threadIdx.x;
    const int bid0 = blockIdx.x;
    // rid-major XCD mapping: dispatch round-robins bid%8 across XCDs; make all
    // SPLIT quarters of a relation land on XCD rid%8 so its 64KB R row is
    // L2-resident (25 rids x 64KB = 1.6MB < 4MB per-XCD L2).
    const int xcd = bid0 & 7;
    const int slot = bid0 >> 3;              // 0..99
    const int rid = xcd + 8 * (slot >> 2);   // 0..199
    const int qtr = slot & 3;
    const int lane = t & 63;
    const int wave = t >> 6;
    const int c2 = lane * 2;

    __shared__ unsigned short list[LISTCAP];
    __shared__ unsigned int wtj[NJ][4];
    __shared__ unsigned int um4[4];
    __shared__ float wsum[4];

    // ---- dtype detect ----
    unsigned int o = ((const unsigned int*)hI)[2 * t + 1] |
                     ((const unsigned int*)rI)[2 * t + 1] |
                     ((const unsigned int*)pI)[2 * t + 1] |
                     ((const unsigned int*)nI)[2 * t + 1];
#pragma unroll
    for (int off = 32; off; off >>= 1) o |= __shfl_xor(o, off, 64);
    if (lane == 0) um4[wave] = o;
    __syncthreads();
    const int is64 = ((um4[0] | um4[1] | um4[2] | um4[3]) == 0u) ? 1 : 0;

    // ---- coalesced scan: element (qbase + j*NTHR + t); ballot-ranked list ----
    const int qbase = qtr * QUARTER;
    unsigned long long bal[NJ];
#pragma unroll
    for (int j = 0; j < NJ; ++j) {
        const int rr = load_idx(rI, qbase + j * NTHR + t, is64);
        bal[j] = __ballot(rr == rid);
        if (lane == 0) wtj[j][wave] = (unsigned int)__popcll(bal[j]);
    }
    __syncthreads();
    int cnt;
    {
        unsigned int run = 0;
        const unsigned long long ltmask = (lane == 63) ? ~0ull >> 1
                                                       : (1ull << lane) - 1ull;
#pragma unroll
        for (int j = 0; j < NJ; ++j) {
            unsigned int wpre = 0, tj = 0;
#pragma unroll
            for (int w = 0; w < 4; ++w) {
                const unsigned int v = wtj[j][w];
                tj += v;
                wpre += (w < wave) ? v : 0;
            }
            if ((bal[j] >> lane) & 1ull) {
                const unsigned int rank =
                    run + wpre + (unsigned int)__popcll(bal[j] & ltmask);
                if (rank < LISTCAP) list[rank] = (unsigned short)(j * NTHR + t);
            }
            run += tj;
        }
        cnt = (int)run;
        if (cnt > LISTCAP) cnt = LISTCAP;
    }
    __syncthreads();  // list complete; no more block syncs until epilogue

    // ---- per-wave independent range ----
    const int per_wave = (cnt + 3) >> 2;
    int lo = wave * per_wave;
    int hi = (wave + 1) * per_wave;
    if (lo > cnt) lo = cnt;
    if (hi > cnt) hi = cnt;

    const float* Rg = rel + (size_t)rid * RD;
    float lsum = 0.f;  // lane-0 meaningful
    float r2w = 0.f;

    for (int e0 = lo; e0 < hi; e0 += EB) {
        int bidx[EB];
        const float* hrow[EB];
#pragma unroll
        for (int i = 0; i < EB; ++i) {
            int e = e0 + i;
            if (e >= hi) e = hi - 1;
            int b = qbase + (int)list[e];
            b = __builtin_amdgcn_readfirstlane(b);
            bidx[i] = b;
            int hix = load_idx(hI, b, is64);
            hix = __builtin_amdgcn_readfirstlane(hix);
            hrow[i] = ent + (size_t)hix * EDIM;
        }

        float2 acc[EB];
#pragma unroll
        for (int i = 0; i < EB; ++i) acc[i] = make_float2(0.f, 0.f);
        float r2p = 0.f;
#pragma unroll 4
        for (int db = 0; db < 32; ++db) {
            float4 hv0 = *(const float4*)(hrow[0] + db * 4);
            float4 hv1 = *(const float4*)(hrow[1] + db * 4);
            float4 hv2 = *(const float4*)(hrow[2] + db * 4);
            float4 hv3 = *(const float4*)(hrow[3] + db * 4);
            float4 hv4 = *(const float4*)(hrow[4] + db * 4);
            float4 hv5 = *(const float4*)(hrow[5] + db * 4);
            float4 hv6 = *(const float4*)(hrow[6] + db * 4);
            float4 hv7 = *(const float4*)(hrow[7] + db * 4);
#pragma unroll
            for (int jj = 0; jj < 4; ++jj) {
                const int d = db * 4 + jj;
                const float2 r2v = *(const float2*)(Rg + d * EDIM + c2);
                r2p = fmaf(r2v.x, r2v.x, fmaf(r2v.y, r2v.y, r2p));
                const float h0 = (jj == 0) ? hv0.x : (jj == 1) ? hv0.y : (jj == 2) ? hv0.z : hv0.w;
                const float h1 = (jj == 0) ? hv1.x : (jj == 1) ? hv1.y : (jj == 2) ? hv1.z : hv1.w;
                const float h2 = (jj == 0) ? hv2.x : (jj == 1) ? hv2.y : (jj == 2) ? hv2.z : hv2.w;
                const float h3 = (jj == 0) ? hv3.x : (jj == 1) ? hv3.y : (jj == 2) ? hv3.z : hv3.w;
                const float h4 = (jj == 0) ? hv4.x : (jj == 1) ? hv4.y : (jj == 2) ? hv4.z : hv4.w;
                const float h5 = (jj == 0) ? hv5.x : (jj == 1) ? hv5.y : (jj == 2) ? hv5.z : hv5.w;
                const float h6 = (jj == 0) ? hv6.x : (jj == 1) ? hv6.y : (jj == 2) ? hv6.z : hv6.w;
                const float h7 = (jj == 0) ? hv7.x : (jj == 1) ? hv7.y : (jj == 2) ? hv7.z : hv7.w;
                acc[0].x = fmaf(r2v.x, h0, acc[0].x); acc[0].y = fmaf(r2v.y, h0, acc[0].y);
                acc[1].x = fmaf(r2v.x, h1, acc[1].x); acc[1].y = fmaf(r2v.y, h1, acc[1].y);
                acc[2].x = fmaf(r2v.x, h2, acc[2].x); acc[2].y = fmaf(r2v.y, h2, acc[2].y);
                acc[3].x = fmaf(r2v.x, h3, acc[3].x); acc[3].y = fmaf(r2v.y, h3, acc[3].y);
                acc[4].x = fmaf(r2v.x, h4, acc[4].x); acc[4].y = fmaf(r2v.y, h4, acc[4].y);
                acc[5].x = fmaf(r2v.x, h5, acc[5].x); acc[5].y = fmaf(r2v.y, h5, acc[5].y);
                acc[6].x = fmaf(r2v.x, h6, acc[6].x); acc[6].y = fmaf(r2v.y, h6, acc[6].y);
                acc[7].x = fmaf(r2v.x, h7, acc[7].x); acc[7].y = fmaf(r2v.y, h7, acc[7].y);
            }
        }
#pragma unroll
        for (int off = 32; off; off >>= 1) r2p += __shfl_xor(r2p, off, 64);
        r2w = r2p;

#pragma unroll
        for (int i = 0; i < EB; ++i) {
            const int b = bidx[i];
            int pi = __builtin_amdgcn_readfirstlane(load_idx(pI, b, is64));
            int ni = __builtin_amdgcn_readfirstlane(load_idx(nI, b, is64));
            const float2 hv2 = *(const float2*)(hrow[i] + c2);
            const float2 tp2 = *(const float2*)(ent + (size_t)pi * EDIM + c2);
            const float2 tn2 = *(const float2*)(ent + (size_t)ni * EDIM + c2);
            float dp = acc[i].x * tp2.x + acc[i].y * tp2.y;
            float dn = acc[i].x * tn2.x + acc[i].y * tn2.y;
            float e2 = hv2.x * hv2.x + hv2.y * hv2.y + tp2.x * tp2.x + tp2.y * tp2.y +
                       tn2.x * tn2.x + tn2.y * tn2.y;
#pragma unroll
            for (int off = 32; off; off >>= 1) {
                dp += __shfl_xor(dp, off, 64);
                dn += __shfl_xor(dn, off, 64);
                e2 += __shfl_xor(e2, off, 64);
            }
            if (lane == 0 && (e0 + i) < hi) {
                const float x = dn - dp;  // neg_score - pos_score
                const float spl = (x > 0.f) ? (x + log1pf(expf(-x))) : log1pf(expf(x));
                lsum += spl + 1e-5f * 0.5f * (e2 + r2w);
            }
        }
    }

    // ---- epilogue: plain store of block partial (unconditional: poison-safe) ----
    if (lane == 0) wsum[wave] = lsum;
    __syncthreads();
    if (t == 0) csum[bid0] = wsum[0] + wsum[1] + wsum[2] + wsum[3];
}

__global__ __launch_bounds__(NTHR) void reduce_kernel(const float* __restrict__ csum,
                                                      float* __restrict__ out) {
    const int t = threadIdx.x;
    float a = 0.f;
    for (int i = t; i < NBLK; i += NTHR) a += csum[i];
#pragma unroll
    for (int off = 32; off; off >>= 1) a += __shfl_down(a, off, 64);
    __shared__ float sm[4];
    if ((t & 63) == 0) sm[t >> 6] = a;
    __syncthreads();
    if (t == 0) out[0] = (sm[0] + sm[1] + sm[2] + sm[3]) * (1.0f / (float)BATCH);
}

extern "C" void kernel_launch(void* const* d_in, const int* in_sizes, int n_in,
                              void* d_out, int out_size, void* d_ws, size_t ws_size,
                              hipStream_t stream) {
    const void* h = d_in[0];
    const void* r = d_in[1];
    const void* pt = d_in[2];
    const void* nt = d_in[3];
    const float* ent = (const float*)d_in[4];
    const float* rel = (const float*)d_in[5];
    float* csum = (float*)d_ws;

    rescal_kernel<<<NBLK, NTHR, 0, stream>>>(h, r, pt, nt, ent, rel, csum);
    reduce_kernel<<<1, NTHR, 0, stream>>>(csum, (float*)d_out);
}